// Round 5
// baseline (831.166 us; speedup 1.0000x reference)
//
#include <hip/hip_runtime.h>
#include <hip/hip_bf16.h>

typedef __hip_bfloat16 bf16;
typedef __attribute__((ext_vector_type(8))) short bf16x8;
typedef __attribute__((ext_vector_type(4))) float f32x4;

#define B_     16
#define N_     1569
#define DIM_   768
#define NHEADS 8
#define HD_    96
#define LK_    393
#define T0_    8
#define H0_    14
#define W0_    14

struct __align__(8) bf16x4s { bf16 a, b, c, d; };

__device__ __forceinline__ float b2f(unsigned short u) {
  union { unsigned int i; float f; } x;
  x.i = ((unsigned int)u) << 16;
  return x.f;
}

// ----------------------------------------------------- fp32 -> bf16 convert
__global__ __launch_bounds__(256) void cvt_f32_bf16(
    const float* __restrict__ in, bf16* __restrict__ out, int n4) {
  int i = blockIdx.x * 256 + threadIdx.x;
  if (i < n4) {
    float4 v = ((const float4*)in)[i];
    bf16x4s o{__float2bfloat16(v.x), __float2bfloat16(v.y),
              __float2bfloat16(v.z), __float2bfloat16(v.w)};
    ((bf16x4s*)out)[i] = o;
  }
}

// ------------------------------------------- transpose fp32 in -> bf16 out
__global__ __launch_bounds__(256) void transpose_f32_bf16(
    const float* __restrict__ in, bf16* __restrict__ out, int R, int C) {
  __shared__ float tile[32][33];
  int c0 = blockIdx.x * 32, r0 = blockIdx.y * 32;
  int tx = threadIdx.x, ty = threadIdx.y;  // 32 x 8
  for (int i = 0; i < 32; i += 8) {
    int r = r0 + ty + i, c = c0 + tx;
    if (r < R && c < C) tile[ty + i][tx] = in[(size_t)r * C + c];
  }
  __syncthreads();
  for (int i = 0; i < 32; i += 8) {
    int c = c0 + ty + i, r = r0 + tx;
    if (c < C && r < R) out[(size_t)c * R + r] = __float2bfloat16(tile[tx][ty + i]);
  }
}

// --------------------------- pool-weight transpose: [96][27] -> [27][96] x3
__global__ __launch_bounds__(256) void prep_pw(
    const float* __restrict__ wq, const float* __restrict__ wk,
    const float* __restrict__ wv, float* __restrict__ outp) {
  int i = blockIdx.x * 256 + threadIdx.x;
  if (i < 2592) {
    int widx = i / 96, x = i % 96;
    outp[i]        = wq[x * 27 + widx];
    outp[2592 + i] = wk[x * 27 + widx];
    outp[5184 + i] = wv[x * 27 + widx];
  }
}

// ------------------------------------------------------- MFMA GEMM, C=A*BT^T
__device__ __forceinline__ void gl_lds16(const bf16* g, bf16* l) {
  __builtin_amdgcn_global_load_lds(
      (const __attribute__((address_space(1))) void*)g,
      (__attribute__((address_space(3))) void*)l, 16, 0, 0);
}

// 1D grid, XCD-chunked bijective swizzle (N-panel-fastest work order),
// BK=64, XOR bank swizzle (pre-swizzled global source + swizzled LDS read).
template <typename OutT>
__global__ __launch_bounds__(256) void gemm_bt(
    const bf16* __restrict__ A, const bf16* __restrict__ BT,
    const float* __restrict__ bias, OutT* __restrict__ C,
    int M, int Nn, int K) {
  constexpr int BM = 128, BN = 128, BK = 64;
  __shared__ __align__(16) bf16 As[BM][BK];   // 16 KB
  __shared__ __align__(16) bf16 Bs[BN][BK];   // 16 KB
  const int tid = threadIdx.x;
  const int lane = tid & 63, wave = tid >> 6;

  // ---- XCD-chunked bijective block swizzle (8 XCDs, m204 variant) ----
  const int nNp = Nn >> 7;
  const int nwg = gridDim.x;
  const int q8 = nwg >> 3, r8 = nwg & 7;
  const int xcd = blockIdx.x & 7, idx = blockIdx.x >> 3;
  const int w = (xcd < r8 ? xcd * (q8 + 1) : r8 * (q8 + 1) + (xcd - r8) * q8) + idx;
  const int bm = (w / nNp) * BM, bn = (w % nNp) * BN;

  const int wm = (wave >> 1) * 64, wn = (wave & 1) * 64;
  const int sl = lane >> 3;                 // row within 8-row staging chunk
  const int sc = ((lane & 7) ^ sl) * 8;     // pre-swizzled source col (elems)

  f32x4 acc[4][4];
#pragma unroll
  for (int i = 0; i < 4; ++i)
#pragma unroll
    for (int j = 0; j < 4; ++j) acc[i][j] = (f32x4){0.f, 0.f, 0.f, 0.f};

  for (int k0 = 0; k0 < K; k0 += BK) {
#pragma unroll
    for (int c = 0; c < 4; ++c) {
      int r0 = wave * 32 + c * 8;
      int arow = bm + r0 + sl;
      if (arow >= M) arow = M - 1;  // clamp: dup loads, masked at store
      gl_lds16(A + (size_t)arow * K + k0 + sc, &As[r0][0]);
      int brow = bn + r0 + sl;      // always < Nn (Nn % 128 == 0)
      gl_lds16(BT + (size_t)brow * K + k0 + sc, &Bs[r0][0]);
    }
    __syncthreads();
    const int fr = lane & 15, q = lane >> 4;
#pragma unroll
    for (int ks = 0; ks < 2; ++ks) {
      const int ph = (((ks << 2) + q) ^ (fr & 7)) << 3;  // swizzled chunk
      bf16x8 af[4], bfr[4];
#pragma unroll
      for (int i = 0; i < 4; ++i) {
        af[i] = *(const bf16x8*)&As[wm + i * 16 + fr][ph];
        bfr[i] = *(const bf16x8*)&Bs[wn + i * 16 + fr][ph];
      }
#pragma unroll
      for (int i = 0; i < 4; ++i)
#pragma unroll
        for (int j = 0; j < 4; ++j)
          acc[i][j] = __builtin_amdgcn_mfma_f32_16x16x32_bf16(af[i], bfr[j],
                                                              acc[i][j], 0, 0, 0);
    }
    __syncthreads();
  }

  const int fr = lane & 15, rg = (lane >> 4) * 4;
#pragma unroll
  for (int j = 0; j < 4; ++j) {
    int col = bn + wn + j * 16 + fr;
    float bv = bias[col];
#pragma unroll
    for (int i = 0; i < 4; ++i) {
#pragma unroll
      for (int r = 0; r < 4; ++r) {
        int row = bm + wm + i * 16 + rg + r;
        if (row < M)
          C[(size_t)row * Nn + col] = (OutT)(acc[i][j][r] + bv);
      }
    }
  }
}

// --------------------------------------------- depthwise 3x3x3 pool + LN
// 256 threads = 16 rows x 16-lane clusters; each thread owns 8 channels.
__global__ __launch_bounds__(256) void pool_ln(
    const bf16* __restrict__ qkv, const float* __restrict__ pwT,
    const float* __restrict__ g, const float* __restrict__ bt,
    bf16* __restrict__ outp, int which, int sHW, int oH, int oW, int Lout) {
  __shared__ float pwl[27 * 104];  // padded fp32 weights, 11.2 KB
  const int tid = threadIdx.x;
  for (int i = tid; i < 2592; i += 256) {
    int widx = i / 96, c = i % 96;
    int cgi = c >> 3, j = c & 7;
    pwl[widx * 104 + cgi * 8 + (cgi >> 2) * 4 + j] = pwT[i];
  }
  __syncthreads();

  const int rloc = tid >> 4;        // 0..15 : row within block
  const int cg = tid & 15;          // 0..15 : channel group (12 active)
  const int orow = blockIdx.x * 16 + rloc;
  if (orow >= Lout) return;         // safe: no barriers after this point
  const int bh = blockIdx.y;
  const int b = bh >> 3, h = bh & 7;
  const bool act = (cg < 12);
  const bf16* base =
      qkv + (size_t)b * N_ * 2304 + which * 768 + h * 96 + cg * 8;

  float acc[8];
#pragma unroll
  for (int j = 0; j < 8; ++j) acc[j] = 0.f;

  if (act) {
    if (orow == 0) {  // cls token: no pooling
      union { uint4 u; bf16 e[8]; } tv;
      tv.u = *(const uint4*)base;
#pragma unroll
      for (int j = 0; j < 8; ++j) acc[j] = (float)tv.e[j];
    } else {
      int pos = orow - 1;
      int ot = pos / (oH * oW), r = pos % (oH * oW);
      int oh = r / oW, ow = r % oW;
      const float* wrow = pwl + cg * 8 + (cg >> 2) * 4;
#pragma unroll
      for (int kt = 0; kt < 3; ++kt) {
        int it = ot + kt - 1;
        if (it < 0 || it >= T0_) continue;
#pragma unroll
        for (int kh = 0; kh < 3; ++kh) {
          int ih = oh * sHW + kh - 1;
          if (ih < 0 || ih >= H0_) continue;
#pragma unroll
          for (int kw = 0; kw < 3; ++kw) {
            int iw = ow * sHW + kw - 1;
            if (iw < 0 || iw >= W0_) continue;
            int n = 1 + (it * H0_ + ih) * W0_ + iw;
            int widx = (kt * 3 + kh) * 3 + kw;
            union { uint4 u; bf16 e[8]; } tv;
            tv.u = *(const uint4*)(base + (size_t)n * 2304);
            const float* w = wrow + widx * 104;
            float wv_[8];
            *(float4*)&wv_[0] = *(const float4*)w;
            *(float4*)&wv_[4] = *(const float4*)(w + 4);
#pragma unroll
            for (int j = 0; j < 8; ++j) acc[j] += (float)tv.e[j] * wv_[j];
          }
        }
      }
    }
  }

  float s = 0.f, s2 = 0.f;
#pragma unroll
  for (int j = 0; j < 8; ++j) { s += acc[j]; s2 += acc[j] * acc[j]; }
#pragma unroll
  for (int mk = 1; mk < 16; mk <<= 1) {
    s += __shfl_xor(s, mk);
    s2 += __shfl_xor(s2, mk);
  }
  float mean = s * (1.f / 96.f);
  float var = s2 * (1.f / 96.f) - mean * mean;
  float rstd = rsqrtf(var + 1e-5f);

  if (act) {
    float gv[8], bv[8];
    *(float4*)&gv[0] = *(const float4*)(g + cg * 8);
    *(float4*)&gv[4] = *(const float4*)(g + cg * 8 + 4);
    *(float4*)&bv[0] = *(const float4*)(bt + cg * 8);
    *(float4*)&bv[4] = *(const float4*)(bt + cg * 8 + 4);
    union { uint4 u; bf16 e[8]; } ov;
#pragma unroll
    for (int j = 0; j < 8; ++j)
      ov.e[j] = __float2bfloat16((acc[j] - mean) * rstd * gv[j] + bv[j]);
    *(uint4*)(outp + ((size_t)bh * Lout + orow) * 96 + cg * 8) = ov.u;
  }
}

// ------------------------- V transpose: [bh][key][96] -> [bh][96][448] (pad 0)
__global__ __launch_bounds__(256) void vtran(
    const bf16* __restrict__ vp, bf16* __restrict__ vt) {
  __shared__ __align__(16) bf16 tile[64][104];
  const int tid = threadIdx.x;
  const int bh = blockIdx.y, kt0 = blockIdx.x * 64;
  const bf16* src = vp + (size_t)bh * LK_ * HD_;
  for (int c = tid; c < 768; c += 256) {
    int row = c / 12, seg = c % 12;
    int key = kt0 + row;
    uint4 v = {0u, 0u, 0u, 0u};
    if (key < LK_) v = *(const uint4*)(src + (size_t)key * HD_ + seg * 8);
    *(uint4*)&tile[row][seg * 8] = v;
  }
  __syncthreads();
  bf16* dst = vt + (size_t)bh * 96 * 448 + kt0;
  for (int c = tid; c < 768; c += 256) {
    int d = c >> 3, ch = c & 7;
    union { uint4 u; bf16 e[8]; } o;
#pragma unroll
    for (int j = 0; j < 8; ++j) o.e[j] = tile[ch * 8 + j][d];
    *(uint4*)(dst + (size_t)d * 448 + ch * 8) = o.u;
  }
}

// ------------------------------------- rel-pos dot tables (precompute kernel)
// relq[bh][p][24] f32: slots 0..7 = t(kt), 8..14 = h(kh), 16..22 = w(kw).
__global__ __launch_bounds__(256) void rel_dots(
    const bf16* __restrict__ qp, const float* __restrict__ rpt,
    const float* __restrict__ rph, const float* __restrict__ rpw,
    float* __restrict__ relq) {
  __shared__ float tab[69 * 100];              // rows: t 0..14, h 15..41, w 42..68
  __shared__ __align__(16) bf16 Qls[64][96];
  const int tid = threadIdx.x;
  const int bh = blockIdx.y;
  const int q0 = blockIdx.x * 64;
  const bf16* qb = qp + (size_t)bh * N_ * HD_;

  for (int i = tid; i < 69 * 24; i += 256) {
    int row = i / 24, c4 = (i % 24) * 4;
    const float* src = row < 15 ? rpt + row * 96
                      : row < 42 ? rph + (row - 15) * 96
                                 : rpw + (row - 42) * 96;
    *(float4*)&tab[row * 100 + c4] = *(const float4*)(src + c4);
  }
  for (int c = tid; c < 768; c += 256) {
    int row = c / 12, seg = c % 12;
    int p = q0 + row;
    if (p >= N_) p = N_ - 1;
    *(uint4*)&Qls[row][seg * 8] = *(const uint4*)(qb + (size_t)p * HD_ + seg * 8);
  }
  __syncthreads();

  const int r8 = tid >> 5, slot = tid & 31;
  if (slot == 15 || slot >= 23) return;  // no barriers after this point
  for (int g = 0; g < 8; ++g) {
    int row = g * 8 + r8;
    int p = q0 + row;
    if (p < 1 || p >= N_) continue;
    int pos = p - 1;
    int qt = pos / 196, rr = pos % 196;
    int qh = rr / 14, qw = rr % 14;
    int ti = slot < 8 ? qt - slot + 7
            : slot < 15 ? 15 + (qh - 2 * (slot - 8) + 12)
                        : 42 + (qw - 2 * (slot - 16) + 12);
    const float* trow = &tab[ti * 100];
    float acc = 0.f;
#pragma unroll
    for (int d4 = 0; d4 < 24; ++d4) {
      float4 w = *(const float4*)(trow + d4 * 4);
      union { uint2 u; unsigned short s[4]; } qv;
      qv.u = *(const uint2*)&Qls[row][d4 * 4];
      acc += w.x * b2f(qv.s[0]) + w.y * b2f(qv.s[1]) +
             w.z * b2f(qv.s[2]) + w.w * b2f(qv.s[3]);
    }
    relq[((size_t)bh * N_ + p) * 24 + slot] = acc;
  }
}

// ------------------------------------------------- MFMA flash attention (v5)
// BARRIER-FREE: K and V^T read directly from global (L1/L2-hot 12 KB tiles);
// Ps + relb are wave-private LDS (same-wave DS ordering). LDS 16 KB.
__global__ __launch_bounds__(256) void attn_fused(
    const bf16* __restrict__ qp, const bf16* __restrict__ kp,
    const bf16* __restrict__ vtb, const float* __restrict__ relq,
    bf16* __restrict__ aout) {
  __shared__ __align__(16) bf16 Ps[4][16][72];   // 9216 B, wave-private
  __shared__ __align__(16) float relb[64][28];   // 7168 B, wave-private rows

  const int tid = threadIdx.x;
  const int wv = tid >> 6, lane = tid & 63;
  const int col = lane & 15, quad = lane >> 4;
  const int bh = blockIdx.y;
  const int b = bh >> 3;
  const int h = bh & 7;
  const int q0 = blockIdx.x * 64;
  const bf16* qb = qp + (size_t)bh * N_ * HD_;
  const bf16* kb = kp + (size_t)bh * LK_ * HD_;
  const bf16* vt = vtb + (size_t)bh * 96 * 448;
  const float scale = 0.102062072615966f;  // 96^-0.5

  // ---- per-wave relb fill (rows wv*16 .. wv*16+15): no barrier needed ----
  {
    const int rbase = wv * 16;
    for (int i = lane; i < 96; i += 64) {
      int rr = i / 6, c4 = i % 6;
      int p = q0 + rbase + rr;
      if (p < N_) {
        uint4 v = *(const uint4*)(relq + ((size_t)bh * N_ + p) * 24 + c4 * 4);
        *(uint4*)&relb[rbase + rr][c4 * 4] = v;
      }
    }
  }

  // ---- Q A-fragments held in registers for whole k-loop ----
  int qrow = q0 + wv * 16 + col;
  if (qrow >= N_) qrow = N_ - 1;
  bf16x8 qa[3];
#pragma unroll
  for (int ks_ = 0; ks_ < 3; ++ks_)
    qa[ks_] = *(const bf16x8*)(qb + (size_t)qrow * HD_ + ks_ * 32 + quad * 8);

  // ---- flash state (4 q rows per lane: row = wv*16 + quad*4 + r) ----
  float mrun[4] = {-1e30f, -1e30f, -1e30f, -1e30f};
  float lrun[4] = {0.f, 0.f, 0.f, 0.f};
  f32x4 oacc[6];
#pragma unroll
  for (int dt = 0; dt < 6; ++dt) oacc[dt] = (f32x4){0.f, 0.f, 0.f, 0.f};

  for (int kt_i = 0; kt_i < 7; ++kt_i) {
    const int kt0 = kt_i * 64;

    // ---- S = Q K^T : K B-frags direct from global (L1-hot tile) ----
    const bf16* kr0;
    const bf16* kr1;
    const bf16* kr2;
    const bf16* kr3;
    {
      int k0g = kt0 + col;
      int k1g = k0g + 16, k2g = k0g + 32, k3g = k0g + 48;
      if (k3g > LK_ - 1) {  // only tail tile needs clamping
        if (k0g > LK_ - 1) k0g = LK_ - 1;
        if (k1g > LK_ - 1) k1g = LK_ - 1;
        if (k2g > LK_ - 1) k2g = LK_ - 1;
        k3g = LK_ - 1;
      }
      kr0 = kb + (size_t)k0g * HD_;
      kr1 = kb + (size_t)k1g * HD_;
      kr2 = kb + (size_t)k2g * HD_;
      kr3 = kb + (size_t)k3g * HD_;
    }
    f32x4 sacc[4];
#pragma unroll
    for (int jt = 0; jt < 4; ++jt) sacc[jt] = (f32x4){0.f, 0.f, 0.f, 0.f};
#pragma unroll
    for (int ks_ = 0; ks_ < 3; ++ks_) {
      const int ko = ks_ * 32 + quad * 8;
      bf16x8 b0 = *(const bf16x8*)(kr0 + ko);
      bf16x8 b1 = *(const bf16x8*)(kr1 + ko);
      bf16x8 b2 = *(const bf16x8*)(kr2 + ko);
      bf16x8 b3 = *(const bf16x8*)(kr3 + ko);
      sacc[0] = __builtin_amdgcn_mfma_f32_16x16x32_bf16(qa[ks_], b0, sacc[0], 0, 0, 0);
      sacc[1] = __builtin_amdgcn_mfma_f32_16x16x32_bf16(qa[ks_], b1, sacc[1], 0, 0, 0);
      sacc[2] = __builtin_amdgcn_mfma_f32_16x16x32_bf16(qa[ks_], b2, sacc[2], 0, 0, 0);
      sacc[3] = __builtin_amdgcn_mfma_f32_16x16x32_bf16(qa[ks_], b3, sacc[3], 0, 0, 0);
    }

    // ---- scale + rel-pos bias + validity ----
    float sv[4][4];  // [jt][reg]
#pragma unroll
    for (int jt = 0; jt < 4; ++jt) {
      int kglob = kt0 + jt * 16 + col;
      bool kvalid = (kglob < LK_);
      int kbod = (kglob >= 1) ? kglob - 1 : 0;
      int kt_ = kbod / 49, krem = kbod % 49;
      int kh_ = krem / 7, kw_ = krem % 7;
#pragma unroll
      for (int r = 0; r < 4; ++r) {
        int qr = wv * 16 + quad * 4 + r;
        int p = q0 + qr;
        float s = sacc[jt][r] * scale;
        if (kvalid && kglob >= 1 && p >= 1 && p < N_)
          s += relb[qr][kt_] + relb[qr][8 + kh_] + relb[qr][16 + kw_];
        if (!kvalid) s = -1e30f;
        sv[jt][r] = s;
      }
    }

    // ---- online softmax (row spread over 16-lane cluster) ----
    float pexp[4][4];
#pragma unroll
    for (int r = 0; r < 4; ++r) {
      float pm = fmaxf(fmaxf(sv[0][r], sv[1][r]), fmaxf(sv[2][r], sv[3][r]));
#pragma unroll
      for (int mk = 1; mk < 16; mk <<= 1) pm = fmaxf(pm, __shfl_xor(pm, mk));
      float mn = fmaxf(mrun[r], pm);
      float alpha = __expf(mrun[r] - mn);
      mrun[r] = mn;
      float rs = 0.f;
#pragma unroll
      for (int jt = 0; jt < 4; ++jt) {
        float e = __expf(sv[jt][r] - mn);
        pexp[jt][r] = e;
        rs += e;
      }
#pragma unroll
      for (int mk = 1; mk < 16; mk <<= 1) rs += __shfl_xor(rs, mk);
      lrun[r] = lrun[r] * alpha + rs;
#pragma unroll
      for (int dt = 0; dt < 6; ++dt) {
        oacc[dt][r] *= alpha;
      }
    }

    // ---- P (C-layout) -> LDS -> A-layout (wave-private; same-wave order) ----
#pragma unroll
    for (int jt = 0; jt < 4; ++jt)
#pragma unroll
      for (int r = 0; r < 4; ++r)
        Ps[wv][quad * 4 + r][jt * 16 + col] = __float2bfloat16(pexp[jt][r]);

    // ---- O += P V : V^T B-frags direct from global (zero-padded keys) ----
#pragma unroll
    for (int ks_ = 0; ks_ < 2; ++ks_) {
      bf16x8 ap = *(const bf16x8*)&Ps[wv][col][ks_ * 32 + quad * 8];
      const int vo = kt0 + ks_ * 32 + quad * 8;
#pragma unroll
      for (int dt = 0; dt < 6; ++dt) {
        bf16x8 bv = *(const bf16x8*)(vt + (size_t)(dt * 16 + col) * 448 + vo);
        oacc[dt] = __builtin_amdgcn_mfma_f32_16x16x32_bf16(ap, bv, oacc[dt], 0, 0, 0);
      }
    }
  }

  // ---- epilogue: O/l + residual q (re-read global, L2-hot), store bf16 ----
#pragma unroll
  for (int r = 0; r < 4; ++r) {
    int qr = wv * 16 + quad * 4 + r;
    int p = q0 + qr;
    if (p >= N_) continue;
    float inv = 1.f / lrun[r];
#pragma unroll
    for (int dt = 0; dt < 6; ++dt) {
      int d = dt * 16 + col;
      float val = oacc[dt][r] * inv;
      if (p >= 1) val += (float)qb[(size_t)p * HD_ + d];
      aout[((size_t)b * N_ + p) * DIM_ + h * HD_ + d] = __float2bfloat16(val);
    }
  }
}

// ------------------------------------------------------------------- launch
extern "C" void kernel_launch(void* const* d_in, const int* in_sizes, int n_in,
                              void* d_out, int out_size, void* d_ws,
                              size_t ws_size, hipStream_t stream) {
  (void)in_sizes; (void)n_in; (void)out_size; (void)ws_size;
  const float* x      = (const float*)d_in[0];
  const float* qkv_w  = (const float*)d_in[1];
  const float* qkv_b  = (const float*)d_in[2];
  const float* pool_q = (const float*)d_in[3];
  const float* pool_k = (const float*)d_in[4];
  const float* pool_v = (const float*)d_in[5];
  const float* ln_q_g = (const float*)d_in[6];
  const float* ln_q_b = (const float*)d_in[7];
  const float* ln_k_g = (const float*)d_in[8];
  const float* ln_k_b = (const float*)d_in[9];
  const float* ln_v_g = (const float*)d_in[10];
  const float* ln_v_b = (const float*)d_in[11];
  const float* rph    = (const float*)d_in[12];
  const float* rpw    = (const float*)d_in[13];
  const float* rpt    = (const float*)d_in[14];
  const float* proj_w = (const float*)d_in[15];
  const float* proj_b = (const float*)d_in[16];

  char* ws = (char*)d_ws;
  bf16* wt_qkv  = (bf16*)(ws);                  // 2304x768 bf16   (3.54 MB)
  bf16* wt_proj = (bf16*)(ws + 3538944);        // 768x768 bf16    (1.18 MB)
  bf16* xb      = (bf16*)(ws + 4718592);        // 25104x768 bf16  (38.6 MB)
  bf16* aout    = xb;                           // reuse: xb dead after gemm#1
  bf16* qkv     = (bf16*)(ws + 43278336);       // 25104x2304 bf16 (115.7 MB)
  float* relq   = (float*)(ws + 43278336);      // aliases qkv (19.3 MB)
  bf16* vtb     = (bf16*)(ws + 63278336);       // aliases qkv (+11.0 MB)
  bf16* qpoolb  = (bf16*)(ws + 158957568);      // 128x1569x96 bf16 (38.6 MB)
  bf16* kpoolb  = (bf16*)(ws + 197517312);      // 128x393x96 bf16  (9.7 MB)
  bf16* vpoolb  = (bf16*)(ws + 207175680);      // 128x393x96 bf16  (9.7 MB)
  float* pwT    = (float*)(ws + 216834048);     // 3x27x96 fp32     (31 KB)
  float* outp   = (float*)d_out;                // fp32 output per reference

  int n4 = (B_ * N_ * DIM_) / 4;
  cvt_f32_bf16<<<(n4 + 255) / 256, 256, 0, stream>>>(x, xb, n4);
  transpose_f32_bf16<<<dim3(72, 24), dim3(32, 8), 0, stream>>>(qkv_w, wt_qkv, 768, 2304);
  transpose_f32_bf16<<<dim3(24, 24), dim3(32, 8), 0, stream>>>(proj_w, wt_proj, 768, 768);
  prep_pw<<<11, 256, 0, stream>>>(pool_q, pool_k, pool_v, pwT);

  gemm_bt<bf16><<<197 * 18, 256, 0, stream>>>(xb, wt_qkv, qkv_b, qkv,
                                              B_ * N_, 3 * DIM_, DIM_);

  pool_ln<<<dim3(99, 128), 256, 0, stream>>>(qkv, pwT, ln_q_g, ln_q_b, qpoolb,
                                             0, 1, 14, 14, N_);
  pool_ln<<<dim3(25, 128), 256, 0, stream>>>(qkv, pwT + 2592, ln_k_g, ln_k_b,
                                             kpoolb, 1, 2, 7, 7, LK_);
  pool_ln<<<dim3(25, 128), 256, 0, stream>>>(qkv, pwT + 5184, ln_v_g, ln_v_b,
                                             vpoolb, 2, 2, 7, 7, LK_);

  // qkv buffer is dead after the pools; relq + vtb alias it.
  vtran<<<dim3(7, 128), 256, 0, stream>>>(vpoolb, vtb);
  rel_dots<<<dim3(25, 128), 256, 0, stream>>>(qpoolb, rpt, rph, rpw, relq);

  attn_fused<<<dim3(25, 128), 256, 0, stream>>>(qpoolb, kpoolb, vtb, relq,
                                                aout);

  gemm_bt<float><<<197 * 6, 256, 0, stream>>>(aout, wt_proj, proj_b, outp,
                                              B_ * N_, DIM_, DIM_);
}

// Round 6
// 754.307 us; speedup vs baseline: 1.1019x; 1.1019x over previous
//
#include <hip/hip_runtime.h>
#include <hip/hip_bf16.h>

typedef __hip_bfloat16 bf16;
typedef __attribute__((ext_vector_type(8))) short bf16x8;
typedef __attribute__((ext_vector_type(4))) float f32x4;

#define B_     16
#define N_     1569
#define DIM_   768
#define NHEADS 8
#define HD_    96
#define LK_    393
#define T0_    8
#define H0_    14
#define W0_    14

struct __align__(8) bf16x4s { bf16 a, b, c, d; };

__device__ __forceinline__ float b2f(unsigned short u) {
  union { unsigned int i; float f; } x;
  x.i = ((unsigned int)u) << 16;
  return x.f;
}

// ----------------------------------------------------- fp32 -> bf16 convert
__global__ __launch_bounds__(256) void cvt_f32_bf16(
    const float* __restrict__ in, bf16* __restrict__ out, int n4) {
  int i = blockIdx.x * 256 + threadIdx.x;
  if (i < n4) {
    float4 v = ((const float4*)in)[i];
    bf16x4s o{__float2bfloat16(v.x), __float2bfloat16(v.y),
              __float2bfloat16(v.z), __float2bfloat16(v.w)};
    ((bf16x4s*)out)[i] = o;
  }
}

// ------------------------------------------- transpose fp32 in -> bf16 out
__global__ __launch_bounds__(256) void transpose_f32_bf16(
    const float* __restrict__ in, bf16* __restrict__ out, int R, int C) {
  __shared__ float tile[32][33];
  int c0 = blockIdx.x * 32, r0 = blockIdx.y * 32;
  int tx = threadIdx.x, ty = threadIdx.y;  // 32 x 8
  for (int i = 0; i < 32; i += 8) {
    int r = r0 + ty + i, c = c0 + tx;
    if (r < R && c < C) tile[ty + i][tx] = in[(size_t)r * C + c];
  }
  __syncthreads();
  for (int i = 0; i < 32; i += 8) {
    int c = c0 + ty + i, r = r0 + tx;
    if (c < C && r < R) out[(size_t)c * R + r] = __float2bfloat16(tile[tx][ty + i]);
  }
}

// --------------------------- pool-weight transpose: [96][27] -> [27][96] x3
__global__ __launch_bounds__(256) void prep_pw(
    const float* __restrict__ wq, const float* __restrict__ wk,
    const float* __restrict__ wv, float* __restrict__ outp) {
  int i = blockIdx.x * 256 + threadIdx.x;
  if (i < 2592) {
    int widx = i / 96, x = i % 96;
    outp[i]        = wq[x * 27 + widx];
    outp[2592 + i] = wk[x * 27 + widx];
    outp[5184 + i] = wv[x * 27 + widx];
  }
}

// ------------------------------------------------------- MFMA GEMM, C=A*BT^T
__device__ __forceinline__ void gl_lds16(const bf16* g, bf16* l) {
  __builtin_amdgcn_global_load_lds(
      (const __attribute__((address_space(1))) void*)g,
      (__attribute__((address_space(3))) void*)l, 16, 0, 0);
}

// 1D grid, XCD-chunked bijective swizzle (N-panel-fastest work order),
// BK=64, XOR bank swizzle (pre-swizzled global source + swizzled LDS read).
template <typename OutT>
__global__ __launch_bounds__(256) void gemm_bt(
    const bf16* __restrict__ A, const bf16* __restrict__ BT,
    const float* __restrict__ bias, OutT* __restrict__ C,
    int M, int Nn, int K) {
  constexpr int BM = 128, BN = 128, BK = 64;
  __shared__ __align__(16) bf16 As[BM][BK];   // 16 KB
  __shared__ __align__(16) bf16 Bs[BN][BK];   // 16 KB
  const int tid = threadIdx.x;
  const int lane = tid & 63, wave = tid >> 6;

  // ---- XCD-chunked bijective block swizzle (8 XCDs, m204 variant) ----
  const int nNp = Nn >> 7;
  const int nwg = gridDim.x;
  const int q8 = nwg >> 3, r8 = nwg & 7;
  const int xcd = blockIdx.x & 7, idx = blockIdx.x >> 3;
  const int w = (xcd < r8 ? xcd * (q8 + 1) : r8 * (q8 + 1) + (xcd - r8) * q8) + idx;
  const int bm = (w / nNp) * BM, bn = (w % nNp) * BN;

  const int wm = (wave >> 1) * 64, wn = (wave & 1) * 64;
  const int sl = lane >> 3;                 // row within 8-row staging chunk
  const int sc = ((lane & 7) ^ sl) * 8;     // pre-swizzled source col (elems)

  f32x4 acc[4][4];
#pragma unroll
  for (int i = 0; i < 4; ++i)
#pragma unroll
    for (int j = 0; j < 4; ++j) acc[i][j] = (f32x4){0.f, 0.f, 0.f, 0.f};

  for (int k0 = 0; k0 < K; k0 += BK) {
#pragma unroll
    for (int c = 0; c < 4; ++c) {
      int r0 = wave * 32 + c * 8;
      int arow = bm + r0 + sl;
      if (arow >= M) arow = M - 1;  // clamp: dup loads, masked at store
      gl_lds16(A + (size_t)arow * K + k0 + sc, &As[r0][0]);
      int brow = bn + r0 + sl;      // always < Nn (Nn % 128 == 0)
      gl_lds16(BT + (size_t)brow * K + k0 + sc, &Bs[r0][0]);
    }
    __syncthreads();
    const int fr = lane & 15, q = lane >> 4;
#pragma unroll
    for (int ks = 0; ks < 2; ++ks) {
      const int ph = (((ks << 2) + q) ^ (fr & 7)) << 3;  // swizzled chunk
      bf16x8 af[4], bfr[4];
#pragma unroll
      for (int i = 0; i < 4; ++i) {
        af[i] = *(const bf16x8*)&As[wm + i * 16 + fr][ph];
        bfr[i] = *(const bf16x8*)&Bs[wn + i * 16 + fr][ph];
      }
#pragma unroll
      for (int i = 0; i < 4; ++i)
#pragma unroll
        for (int j = 0; j < 4; ++j)
          acc[i][j] = __builtin_amdgcn_mfma_f32_16x16x32_bf16(af[i], bfr[j],
                                                              acc[i][j], 0, 0, 0);
    }
    __syncthreads();
  }

  const int fr = lane & 15, rg = (lane >> 4) * 4;
#pragma unroll
  for (int j = 0; j < 4; ++j) {
    int col = bn + wn + j * 16 + fr;
    float bv = bias[col];
#pragma unroll
    for (int i = 0; i < 4; ++i) {
#pragma unroll
      for (int r = 0; r < 4; ++r) {
        int row = bm + wm + i * 16 + rg + r;
        if (row < M)
          C[(size_t)row * Nn + col] = (OutT)(acc[i][j][r] + bv);
      }
    }
  }
}

// --------------------------------------------- depthwise 3x3x3 pool + LN
// 256 threads = 16 rows x 16-lane clusters; each thread owns 8 channels.
__global__ __launch_bounds__(256) void pool_ln(
    const bf16* __restrict__ qkv, const float* __restrict__ pwT,
    const float* __restrict__ g, const float* __restrict__ bt,
    bf16* __restrict__ outp, int which, int sHW, int oH, int oW, int Lout) {
  __shared__ float pwl[27 * 104];  // padded fp32 weights, 11.2 KB
  const int tid = threadIdx.x;
  for (int i = tid; i < 2592; i += 256) {
    int widx = i / 96, c = i % 96;
    int cgi = c >> 3, j = c & 7;
    pwl[widx * 104 + cgi * 8 + (cgi >> 2) * 4 + j] = pwT[i];
  }
  __syncthreads();

  const int rloc = tid >> 4;        // 0..15 : row within block
  const int cg = tid & 15;          // 0..15 : channel group (12 active)
  const int orow = blockIdx.x * 16 + rloc;
  if (orow >= Lout) return;         // safe: no barriers after this point
  const int bh = blockIdx.y;
  const int b = bh >> 3, h = bh & 7;
  const bool act = (cg < 12);
  const bf16* base =
      qkv + (size_t)b * N_ * 2304 + which * 768 + h * 96 + cg * 8;

  float acc[8];
#pragma unroll
  for (int j = 0; j < 8; ++j) acc[j] = 0.f;

  if (act) {
    if (orow == 0) {  // cls token: no pooling
      union { uint4 u; bf16 e[8]; } tv;
      tv.u = *(const uint4*)base;
#pragma unroll
      for (int j = 0; j < 8; ++j) acc[j] = (float)tv.e[j];
    } else {
      int pos = orow - 1;
      int ot = pos / (oH * oW), r = pos % (oH * oW);
      int oh = r / oW, ow = r % oW;
      const float* wrow = pwl + cg * 8 + (cg >> 2) * 4;
#pragma unroll
      for (int kt = 0; kt < 3; ++kt) {
        int it = ot + kt - 1;
        if (it < 0 || it >= T0_) continue;
#pragma unroll
        for (int kh = 0; kh < 3; ++kh) {
          int ih = oh * sHW + kh - 1;
          if (ih < 0 || ih >= H0_) continue;
#pragma unroll
          for (int kw = 0; kw < 3; ++kw) {
            int iw = ow * sHW + kw - 1;
            if (iw < 0 || iw >= W0_) continue;
            int n = 1 + (it * H0_ + ih) * W0_ + iw;
            int widx = (kt * 3 + kh) * 3 + kw;
            union { uint4 u; bf16 e[8]; } tv;
            tv.u = *(const uint4*)(base + (size_t)n * 2304);
            const float* w = wrow + widx * 104;
            float wv_[8];
            *(float4*)&wv_[0] = *(const float4*)w;
            *(float4*)&wv_[4] = *(const float4*)(w + 4);
#pragma unroll
            for (int j = 0; j < 8; ++j) acc[j] += (float)tv.e[j] * wv_[j];
          }
        }
      }
    }
  }

  float s = 0.f, s2 = 0.f;
#pragma unroll
  for (int j = 0; j < 8; ++j) { s += acc[j]; s2 += acc[j] * acc[j]; }
#pragma unroll
  for (int mk = 1; mk < 16; mk <<= 1) {
    s += __shfl_xor(s, mk);
    s2 += __shfl_xor(s2, mk);
  }
  float mean = s * (1.f / 96.f);
  float var = s2 * (1.f / 96.f) - mean * mean;
  float rstd = rsqrtf(var + 1e-5f);

  if (act) {
    float gv[8], bv[8];
    *(float4*)&gv[0] = *(const float4*)(g + cg * 8);
    *(float4*)&gv[4] = *(const float4*)(g + cg * 8 + 4);
    *(float4*)&bv[0] = *(const float4*)(bt + cg * 8);
    *(float4*)&bv[4] = *(const float4*)(bt + cg * 8 + 4);
    union { uint4 u; bf16 e[8]; } ov;
#pragma unroll
    for (int j = 0; j < 8; ++j)
      ov.e[j] = __float2bfloat16((acc[j] - mean) * rstd * gv[j] + bv[j]);
    *(uint4*)(outp + ((size_t)bh * Lout + orow) * 96 + cg * 8) = ov.u;
  }
}

// ------------------------- V transpose: [bh][key][96] -> [bh][96][448] (pad 0)
__global__ __launch_bounds__(256) void vtran(
    const bf16* __restrict__ vp, bf16* __restrict__ vt) {
  __shared__ __align__(16) bf16 tile[64][104];
  const int tid = threadIdx.x;
  const int bh = blockIdx.y, kt0 = blockIdx.x * 64;
  const bf16* src = vp + (size_t)bh * LK_ * HD_;
  for (int c = tid; c < 768; c += 256) {
    int row = c / 12, seg = c % 12;
    int key = kt0 + row;
    uint4 v = {0u, 0u, 0u, 0u};
    if (key < LK_) v = *(const uint4*)(src + (size_t)key * HD_ + seg * 8);
    *(uint4*)&tile[row][seg * 8] = v;
  }
  __syncthreads();
  bf16* dst = vt + (size_t)bh * 96 * 448 + kt0;
  for (int c = tid; c < 768; c += 256) {
    int d = c >> 3, ch = c & 7;
    union { uint4 u; bf16 e[8]; } o;
#pragma unroll
    for (int j = 0; j < 8; ++j) o.e[j] = tile[ch * 8 + j][d];
    *(uint4*)(dst + (size_t)d * 448 + ch * 8) = o.u;
  }
}

// ------------------------------------- rel-pos dot tables (precompute kernel)
// relq[bh][p][24] f32: slots 0..7 = t(kt), 8..14 = h(kh), 16..22 = w(kw).
__global__ __launch_bounds__(256) void rel_dots(
    const bf16* __restrict__ qp, const float* __restrict__ rpt,
    const float* __restrict__ rph, const float* __restrict__ rpw,
    float* __restrict__ relq) {
  __shared__ float tab[69 * 100];              // rows: t 0..14, h 15..41, w 42..68
  __shared__ __align__(16) bf16 Qls[64][96];
  const int tid = threadIdx.x;
  const int bh = blockIdx.y;
  const int q0 = blockIdx.x * 64;
  const bf16* qb = qp + (size_t)bh * N_ * HD_;

  for (int i = tid; i < 69 * 24; i += 256) {
    int row = i / 24, c4 = (i % 24) * 4;
    const float* src = row < 15 ? rpt + row * 96
                      : row < 42 ? rph + (row - 15) * 96
                                 : rpw + (row - 42) * 96;
    *(float4*)&tab[row * 100 + c4] = *(const float4*)(src + c4);
  }
  for (int c = tid; c < 768; c += 256) {
    int row = c / 12, seg = c % 12;
    int p = q0 + row;
    if (p >= N_) p = N_ - 1;
    *(uint4*)&Qls[row][seg * 8] = *(const uint4*)(qb + (size_t)p * HD_ + seg * 8);
  }
  __syncthreads();

  const int r8 = tid >> 5, slot = tid & 31;
  if (slot == 15 || slot >= 23) return;  // no barriers after this point
  for (int g = 0; g < 8; ++g) {
    int row = g * 8 + r8;
    int p = q0 + row;
    if (p < 1 || p >= N_) continue;
    int pos = p - 1;
    int qt = pos / 196, rr = pos % 196;
    int qh = rr / 14, qw = rr % 14;
    int ti = slot < 8 ? qt - slot + 7
            : slot < 15 ? 15 + (qh - 2 * (slot - 8) + 12)
                        : 42 + (qw - 2 * (slot - 16) + 12);
    const float* trow = &tab[ti * 100];
    float acc = 0.f;
#pragma unroll
    for (int d4 = 0; d4 < 24; ++d4) {
      float4 w = *(const float4*)(trow + d4 * 4);
      union { uint2 u; unsigned short s[4]; } qv;
      qv.u = *(const uint2*)&Qls[row][d4 * 4];
      acc += w.x * b2f(qv.s[0]) + w.y * b2f(qv.s[1]) +
             w.z * b2f(qv.s[2]) + w.w * b2f(qv.s[3]);
    }
    relq[((size_t)bh * N_ + p) * 24 + slot] = acc;
  }
}

// ------------------------------------------------- MFMA flash attention (v6)
// R3's proven 2-barrier structure; V staged via global_load_lds from the
// pre-transposed vtb (linear LDS dest + pre-swizzled global src => identical
// VtS image to R3). K reg-staged into padded Ks as R3. LDS 40960 B exactly
// (4 blocks/CU). Q A-frags in registers; rel-pos bias precomputed.
__global__ __launch_bounds__(256) void attn_fused(
    const bf16* __restrict__ qp, const bf16* __restrict__ kp,
    const bf16* __restrict__ vtb, const float* __restrict__ relq,
    bf16* __restrict__ aout) {
  __shared__ __align__(16) bf16 Ks[64][104];    // 13312 B (pad 96->104)
  __shared__ __align__(16) bf16 VtS[96 * 64];   // 12288 B [d][key^swz]
  __shared__ __align__(16) bf16 Ps[4][16][72];  //  9216 B per-wave P tile
  __shared__ float relb[64][24];                //  6144 B

  const int tid = threadIdx.x;
  const int wv = tid >> 6, lane = tid & 63;
  const int col = lane & 15, quad = lane >> 4;
  const int bh = blockIdx.y;
  const int b = bh >> 3;
  const int h = bh & 7;
  const int q0 = blockIdx.x * 64;
  const bf16* qb = qp + (size_t)bh * N_ * HD_;
  const bf16* kb = kp + (size_t)bh * LK_ * HD_;
  const bf16* vt = vtb + (size_t)bh * 96 * 448;
  const float scale = 0.102062072615966f;  // 96^-0.5

  // ---- fill relb from precomputed global (vectorized; visible after (2)) ----
  {
    int nrow = N_ - q0;
    if (nrow > 64) nrow = 64;
    int n4 = nrow * 6;  // uint4 count (24 f32 per row)
    const uint4* src = (const uint4*)(relq + ((size_t)bh * N_ + q0) * 24);
    for (int i = tid; i < n4; i += 256) ((uint4*)relb)[i] = src[i];
  }

  // ---- Q A-fragments held in registers for whole k-loop ----
  int qrow = q0 + wv * 16 + col;
  if (qrow >= N_) qrow = N_ - 1;
  bf16x8 qa[3];
#pragma unroll
  for (int ks_ = 0; ks_ < 3; ++ks_)
    qa[ks_] = *(const bf16x8*)(qb + (size_t)qrow * HD_ + ks_ * 32 + quad * 8);

  // ---- hoisted staging geometry ----
  int krow[3], kseg[3];       // K: thread's 3 chunks of the 64x96 tile
  int voff[3];                // V: per-lane pre-swizzled source elem offset
  bf16* vdst[3];              // V: wave-uniform LDS dest base
#pragma unroll
  for (int i = 0; i < 3; ++i) {
    int c = tid + i * 256;
    krow[i] = c / 12;
    kseg[i] = (c % 12) * 8;
    int ci = wv * 192 + i * 64 + lane;       // chunk index in VtS (16B units)
    int d = ci >> 3, j0 = (ci & 7) * 8;
    int c_ = (d ^ (d >> 3)) & 7;
    voff[i] = d * 448 + (j0 ^ (c_ * 8));
    vdst[i] = (bf16*)VtS + (size_t)(wv * 192 + i * 64) * 8;
  }

  // ---- flash state (4 q rows per lane: row = wv*16 + quad*4 + r) ----
  float mrun[4] = {-1e30f, -1e30f, -1e30f, -1e30f};
  float lrun[4] = {0.f, 0.f, 0.f, 0.f};
  f32x4 oacc[6];
#pragma unroll
  for (int dt = 0; dt < 6; ++dt) oacc[dt] = (f32x4){0.f, 0.f, 0.f, 0.f};

  for (int kt_i = 0; kt_i < 7; ++kt_i) {
    const int kt0 = kt_i * 64;
    __syncthreads();  // (1) prior reads of Ks/VtS done; relb visible (iter 0)
    // ---- stage K (reg path, padded rows) + V^T (global_load_lds, linear) ----
#pragma unroll
    for (int i = 0; i < 3; ++i) {
      int key = kt0 + krow[i];
      if (key >= LK_) key = LK_ - 1;
      *(uint4*)&Ks[krow[i]][kseg[i]] =
          *(const uint4*)(kb + (size_t)key * HD_ + kseg[i]);
      gl_lds16(vt + voff[i] + kt0, vdst[i]);
    }
    __syncthreads();  // (2) tiles ready (compiler drains vmcnt+lgkmcnt)

    // ---- S = Q K^T ----
    f32x4 sacc[4];
#pragma unroll
    for (int jt = 0; jt < 4; ++jt) sacc[jt] = (f32x4){0.f, 0.f, 0.f, 0.f};
#pragma unroll
    for (int ks_ = 0; ks_ < 3; ++ks_) {
#pragma unroll
      for (int jt = 0; jt < 4; ++jt) {
        bf16x8 bk = *(const bf16x8*)&Ks[jt * 16 + col][ks_ * 32 + quad * 8];
        sacc[jt] = __builtin_amdgcn_mfma_f32_16x16x32_bf16(qa[ks_], bk, sacc[jt], 0, 0, 0);
      }
    }

    // ---- scale + rel-pos bias + validity ----
    float sv[4][4];  // [jt][reg]
#pragma unroll
    for (int jt = 0; jt < 4; ++jt) {
      int kglob = kt0 + jt * 16 + col;
      bool kvalid = (kglob < LK_);
      int kbod = (kglob >= 1) ? kglob - 1 : 0;
      int kt_ = kbod / 49, krem = kbod % 49;
      int kh_ = krem / 7, kw_ = krem % 7;
#pragma unroll
      for (int r = 0; r < 4; ++r) {
        int qr = wv * 16 + quad * 4 + r;
        int p = q0 + qr;
        float s = sacc[jt][r] * scale;
        if (kvalid && kglob >= 1 && p >= 1 && p < N_)
          s += relb[qr][kt_] + relb[qr][8 + kh_] + relb[qr][16 + kw_];
        if (!kvalid) s = -1e30f;
        sv[jt][r] = s;
      }
    }

    // ---- online softmax (row spread over 16-lane cluster) ----
    float pexp[4][4];
#pragma unroll
    for (int r = 0; r < 4; ++r) {
      float pm = fmaxf(fmaxf(sv[0][r], sv[1][r]), fmaxf(sv[2][r], sv[3][r]));
#pragma unroll
      for (int mk = 1; mk < 16; mk <<= 1) pm = fmaxf(pm, __shfl_xor(pm, mk));
      float mn = fmaxf(mrun[r], pm);
      float alpha = __expf(mrun[r] - mn);
      mrun[r] = mn;
      float rs = 0.f;
#pragma unroll
      for (int jt = 0; jt < 4; ++jt) {
        float e = __expf(sv[jt][r] - mn);
        pexp[jt][r] = e;
        rs += e;
      }
#pragma unroll
      for (int mk = 1; mk < 16; mk <<= 1) rs += __shfl_xor(rs, mk);
      lrun[r] = lrun[r] * alpha + rs;
#pragma unroll
      for (int dt = 0; dt < 6; ++dt) {
        oacc[dt][r] *= alpha;
      }
    }

    // ---- P (C-layout) -> LDS -> A-layout (wave-private region) ----
#pragma unroll
    for (int jt = 0; jt < 4; ++jt)
#pragma unroll
      for (int r = 0; r < 4; ++r)
        Ps[wv][quad * 4 + r][jt * 16 + col] = __float2bfloat16(pexp[jt][r]);
    // same-wave DS ordering: compiler's lgkmcnt wait orders write->read

    // ---- O += P V ----
#pragma unroll
    for (int ks_ = 0; ks_ < 2; ++ks_) {
      bf16x8 ap = *(const bf16x8*)&Ps[wv][col][ks_ * 32 + quad * 8];
#pragma unroll
      for (int dt = 0; dt < 6; ++dt) {
        int d = dt * 16 + col;
        int c_ = (d ^ (d >> 3)) & 7;
        bf16x8 bv =
            *(const bf16x8*)&VtS[d * 64 + ((ks_ * 32 + quad * 8) ^ (c_ << 3))];
        oacc[dt] = __builtin_amdgcn_mfma_f32_16x16x32_bf16(ap, bv, oacc[dt], 0, 0, 0);
      }
    }
  }

  // ---- epilogue: O/l + residual q (re-read global, L2-hot), store bf16 ----
#pragma unroll
  for (int r = 0; r < 4; ++r) {
    int qr = wv * 16 + quad * 4 + r;
    int p = q0 + qr;
    if (p >= N_) continue;
    float inv = 1.f / lrun[r];
#pragma unroll
    for (int dt = 0; dt < 6; ++dt) {
      int d = dt * 16 + col;
      float val = oacc[dt][r] * inv;
      if (p >= 1) val += (float)qb[(size_t)p * HD_ + d];
      aout[((size_t)b * N_ + p) * DIM_ + h * HD_ + d] = __float2bfloat16(val);
    }
  }
}

// ------------------------------------------------------------------- launch
extern "C" void kernel_launch(void* const* d_in, const int* in_sizes, int n_in,
                              void* d_out, int out_size, void* d_ws,
                              size_t ws_size, hipStream_t stream) {
  (void)in_sizes; (void)n_in; (void)out_size; (void)ws_size;
  const float* x      = (const float*)d_in[0];
  const float* qkv_w  = (const float*)d_in[1];
  const float* qkv_b  = (const float*)d_in[2];
  const float* pool_q = (const float*)d_in[3];
  const float* pool_k = (const float*)d_in[4];
  const float* pool_v = (const float*)d_in[5];
  const float* ln_q_g = (const float*)d_in[6];
  const float* ln_q_b = (const float*)d_in[7];
  const float* ln_k_g = (const float*)d_in[8];
  const float* ln_k_b = (const float*)d_in[9];
  const float* ln_v_g = (const float*)d_in[10];
  const float* ln_v_b = (const float*)d_in[11];
  const float* rph    = (const float*)d_in[12];
  const float* rpw    = (const float*)d_in[13];
  const float* rpt    = (const float*)d_in[14];
  const float* proj_w = (const float*)d_in[15];
  const float* proj_b = (const float*)d_in[16];

  char* ws = (char*)d_ws;
  bf16* wt_qkv  = (bf16*)(ws);                  // 2304x768 bf16   (3.54 MB)
  bf16* wt_proj = (bf16*)(ws + 3538944);        // 768x768 bf16    (1.18 MB)
  bf16* xb      = (bf16*)(ws + 4718592);        // 25104x768 bf16  (38.6 MB)
  bf16* aout    = xb;                           // reuse: xb dead after gemm#1
  bf16* qkv     = (bf16*)(ws + 43278336);       // 25104x2304 bf16 (115.7 MB)
  float* relq   = (float*)(ws + 43278336);      // aliases qkv (19.3 MB)
  bf16* vtb     = (bf16*)(ws + 63278336);       // aliases qkv (+11.0 MB)
  bf16* qpoolb  = (bf16*)(ws + 158957568);      // 128x1569x96 bf16 (38.6 MB)
  bf16* kpoolb  = (bf16*)(ws + 197517312);      // 128x393x96 bf16  (9.7 MB)
  bf16* vpoolb  = (bf16*)(ws + 207175680);      // 128x393x96 bf16  (9.7 MB)
  float* pwT    = (float*)(ws + 216834048);     // 3x27x96 fp32     (31 KB)
  float* outp   = (float*)d_out;                // fp32 output per reference

  int n4 = (B_ * N_ * DIM_) / 4;
  cvt_f32_bf16<<<(n4 + 255) / 256, 256, 0, stream>>>(x, xb, n4);
  transpose_f32_bf16<<<dim3(72, 24), dim3(32, 8), 0, stream>>>(qkv_w, wt_qkv, 768, 2304);
  transpose_f32_bf16<<<dim3(24, 24), dim3(32, 8), 0, stream>>>(proj_w, wt_proj, 768, 768);
  prep_pw<<<11, 256, 0, stream>>>(pool_q, pool_k, pool_v, pwT);

  gemm_bt<bf16><<<197 * 18, 256, 0, stream>>>(xb, wt_qkv, qkv_b, qkv,
                                              B_ * N_, 3 * DIM_, DIM_);

  pool_ln<<<dim3(99, 128), 256, 0, stream>>>(qkv, pwT, ln_q_g, ln_q_b, qpoolb,
                                             0, 1, 14, 14, N_);
  pool_ln<<<dim3(25, 128), 256, 0, stream>>>(qkv, pwT + 2592, ln_k_g, ln_k_b,
                                             kpoolb, 1, 2, 7, 7, LK_);
  pool_ln<<<dim3(25, 128), 256, 0, stream>>>(qkv, pwT + 5184, ln_v_g, ln_v_b,
                                             vpoolb, 2, 2, 7, 7, LK_);

  // qkv buffer is dead after the pools; relq + vtb alias it.
  vtran<<<dim3(7, 128), 256, 0, stream>>>(vpoolb, vtb);
  rel_dots<<<dim3(25, 128), 256, 0, stream>>>(qpoolb, rpt, rph, rpw, relq);

  attn_fused<<<dim3(25, 128), 256, 0, stream>>>(qpoolb, kpoolb, vtb, relq,
                                                aout);

  gemm_bt<float><<<197 * 6, 256, 0, stream>>>(aout, wt_proj, proj_b, outp,
                                              B_ * N_, DIM_, DIM_);
}

// Round 7
// 706.938 us; speedup vs baseline: 1.1757x; 1.0670x over previous
//
#include <hip/hip_runtime.h>
#include <hip/hip_bf16.h>

typedef __hip_bfloat16 bf16;
typedef __attribute__((ext_vector_type(8))) short bf16x8;
typedef __attribute__((ext_vector_type(4))) float f32x4;

#define B_     16
#define N_     1569
#define DIM_   768
#define NHEADS 8
#define HD_    96
#define LK_    393
#define T0_    8
#define H0_    14
#define W0_    14

struct __align__(8) bf16x4s { bf16 a, b, c, d; };

__device__ __forceinline__ float b2f(unsigned short u) {
  union { unsigned int i; float f; } x;
  x.i = ((unsigned int)u) << 16;
  return x.f;
}

// ----------------------------------------------------- fp32 -> bf16 convert
__global__ __launch_bounds__(256) void cvt_f32_bf16(
    const float* __restrict__ in, bf16* __restrict__ out, int n4) {
  int i = blockIdx.x * 256 + threadIdx.x;
  if (i < n4) {
    float4 v = ((const float4*)in)[i];
    bf16x4s o{__float2bfloat16(v.x), __float2bfloat16(v.y),
              __float2bfloat16(v.z), __float2bfloat16(v.w)};
    ((bf16x4s*)out)[i] = o;
  }
}

// ------------------------------------------- transpose fp32 in -> bf16 out
__global__ __launch_bounds__(256) void transpose_f32_bf16(
    const float* __restrict__ in, bf16* __restrict__ out, int R, int C) {
  __shared__ float tile[32][33];
  int c0 = blockIdx.x * 32, r0 = blockIdx.y * 32;
  int tx = threadIdx.x, ty = threadIdx.y;  // 32 x 8
  for (int i = 0; i < 32; i += 8) {
    int r = r0 + ty + i, c = c0 + tx;
    if (r < R && c < C) tile[ty + i][tx] = in[(size_t)r * C + c];
  }
  __syncthreads();
  for (int i = 0; i < 32; i += 8) {
    int c = c0 + ty + i, r = r0 + tx;
    if (c < C && r < R) out[(size_t)c * R + r] = __float2bfloat16(tile[tx][ty + i]);
  }
}

// --------------------------- pool-weight transpose: [96][27] -> [27][96] x3
__global__ __launch_bounds__(256) void prep_pw(
    const float* __restrict__ wq, const float* __restrict__ wk,
    const float* __restrict__ wv, float* __restrict__ outp) {
  int i = blockIdx.x * 256 + threadIdx.x;
  if (i < 2592) {
    int widx = i / 96, x = i % 96;
    outp[i]        = wq[x * 27 + widx];
    outp[2592 + i] = wk[x * 27 + widx];
    outp[5184 + i] = wv[x * 27 + widx];
  }
}

// ------------------------------------------------------- MFMA GEMM, C=A*BT^T
__device__ __forceinline__ void gl_lds16(const bf16* g, bf16* l) {
  __builtin_amdgcn_global_load_lds(
      (const __attribute__((address_space(1))) void*)g,
      (__attribute__((address_space(3))) void*)l, 16, 0, 0);
}

// 1D grid, XCD-chunked bijective swizzle (N-panel-fastest work order),
// BK=64, XOR bank swizzle. bf16 output path stages C through LDS so all
// global stores are coalesced 16B (avoids partial-line RMW amplification).
template <typename OutT>
__global__ __launch_bounds__(256) void gemm_bt(
    const bf16* __restrict__ A, const bf16* __restrict__ BT,
    const float* __restrict__ bias, OutT* __restrict__ C,
    int M, int Nn, int K) {
  constexpr int BM = 128, BN = 128, BK = 64;
  __shared__ __align__(16) char smem[BM * BK * 2 + BN * BK * 2];  // 32 KB
  bf16 (*As)[BK] = (bf16(*)[BK])smem;
  bf16 (*Bs)[BK] = (bf16(*)[BK])(smem + BM * BK * 2);
  const int tid = threadIdx.x;
  const int lane = tid & 63, wave = tid >> 6;

  // ---- XCD-chunked bijective block swizzle (8 XCDs, m204 variant) ----
  const int nNp = Nn >> 7;
  const int nwg = gridDim.x;
  const int q8 = nwg >> 3, r8 = nwg & 7;
  const int xcd = blockIdx.x & 7, idx = blockIdx.x >> 3;
  const int w = (xcd < r8 ? xcd * (q8 + 1) : r8 * (q8 + 1) + (xcd - r8) * q8) + idx;
  const int bm = (w / nNp) * BM, bn = (w % nNp) * BN;

  const int wm = (wave >> 1) * 64, wn = (wave & 1) * 64;
  const int sl = lane >> 3;                 // row within 8-row staging chunk
  const int sc = ((lane & 7) ^ sl) * 8;     // pre-swizzled source col (elems)

  f32x4 acc[4][4];
#pragma unroll
  for (int i = 0; i < 4; ++i)
#pragma unroll
    for (int j = 0; j < 4; ++j) acc[i][j] = (f32x4){0.f, 0.f, 0.f, 0.f};

  for (int k0 = 0; k0 < K; k0 += BK) {
#pragma unroll
    for (int c = 0; c < 4; ++c) {
      int r0 = wave * 32 + c * 8;
      int arow = bm + r0 + sl;
      if (arow >= M) arow = M - 1;  // clamp: dup loads, masked at store
      gl_lds16(A + (size_t)arow * K + k0 + sc, &As[r0][0]);
      int brow = bn + r0 + sl;      // always < Nn (Nn % 128 == 0)
      gl_lds16(BT + (size_t)brow * K + k0 + sc, &Bs[r0][0]);
    }
    __syncthreads();
    const int fr = lane & 15, q = lane >> 4;
#pragma unroll
    for (int ks = 0; ks < 2; ++ks) {
      const int ph = (((ks << 2) + q) ^ (fr & 7)) << 3;  // swizzled chunk
      bf16x8 af[4], bfr[4];
#pragma unroll
      for (int i = 0; i < 4; ++i) {
        af[i] = *(const bf16x8*)&As[wm + i * 16 + fr][ph];
        bfr[i] = *(const bf16x8*)&Bs[wn + i * 16 + fr][ph];
      }
#pragma unroll
      for (int i = 0; i < 4; ++i)
#pragma unroll
        for (int j = 0; j < 4; ++j)
          acc[i][j] = __builtin_amdgcn_mfma_f32_16x16x32_bf16(af[i], bfr[j],
                                                              acc[i][j], 0, 0, 0);
    }
    __syncthreads();
  }

  const int fr = lane & 15, rg = (lane >> 4) * 4;
  if constexpr (sizeof(OutT) == 2) {
    // ---- LDS-staged epilogue: coalesced 16B stores, no partial-line RMW ----
    // Chunk-XOR swizzle: write col ^ (quad<<4), read seg ^ ((row>>2&3)<<1).
    bf16 (*Cs)[BN] = (bf16(*)[BN])smem;  // 32 KB, aliases As/Bs (loop done)
#pragma unroll
    for (int j = 0; j < 4; ++j) {
      int lc = wn + j * 16 + fr;
      float bv = bias[bn + lc];
#pragma unroll
      for (int i = 0; i < 4; ++i) {
#pragma unroll
        for (int r = 0; r < 4; ++r) {
          int lr = wm + i * 16 + rg + r;
          int pc = lc ^ ((((lr >> 2) & 3)) << 4);
          Cs[lr][pc] = __float2bfloat16(acc[i][j][r] + bv);
        }
      }
    }
    __syncthreads();
#pragma unroll
    for (int k = 0; k < 8; ++k) {
      int c = tid + k * 256;
      int row = c >> 4, seg = c & 15;
      int grow = bm + row;
      int ps = seg ^ (((row >> 2) & 3) << 1);
      if (grow < M)
        *(uint4*)&C[(size_t)grow * Nn + bn + seg * 8] =
            *(const uint4*)&Cs[row][ps * 8];
    }
  } else {
    // f32 path: quarter-wave writes 64B contiguous = full line, no RMW
#pragma unroll
    for (int j = 0; j < 4; ++j) {
      int col = bn + wn + j * 16 + fr;
      float bv = bias[col];
#pragma unroll
      for (int i = 0; i < 4; ++i) {
#pragma unroll
        for (int r = 0; r < 4; ++r) {
          int row = bm + wm + i * 16 + rg + r;
          if (row < M)
            C[(size_t)row * Nn + col] = (OutT)(acc[i][j][r] + bv);
        }
      }
    }
  }
}

// --------------------------------------------- depthwise 3x3x3 pool + LN
// 256 threads = 16 rows x 16-lane clusters; each thread owns 8 channels.
__global__ __launch_bounds__(256) void pool_ln(
    const bf16* __restrict__ qkv, const float* __restrict__ pwT,
    const float* __restrict__ g, const float* __restrict__ bt,
    bf16* __restrict__ outp, int which, int sHW, int oH, int oW, int Lout) {
  __shared__ float pwl[27 * 104];  // padded fp32 weights, 11.2 KB
  const int tid = threadIdx.x;
  for (int i = tid; i < 2592; i += 256) {
    int widx = i / 96, c = i % 96;
    int cgi = c >> 3, j = c & 7;
    pwl[widx * 104 + cgi * 8 + (cgi >> 2) * 4 + j] = pwT[i];
  }
  __syncthreads();

  const int rloc = tid >> 4;        // 0..15 : row within block
  const int cg = tid & 15;          // 0..15 : channel group (12 active)
  const int orow = blockIdx.x * 16 + rloc;
  if (orow >= Lout) return;         // safe: no barriers after this point
  const int bh = blockIdx.y;
  const int b = bh >> 3, h = bh & 7;
  const bool act = (cg < 12);
  const bf16* base =
      qkv + (size_t)b * N_ * 2304 + which * 768 + h * 96 + cg * 8;

  float acc[8];
#pragma unroll
  for (int j = 0; j < 8; ++j) acc[j] = 0.f;

  if (act) {
    if (orow == 0) {  // cls token: no pooling
      union { uint4 u; bf16 e[8]; } tv;
      tv.u = *(const uint4*)base;
#pragma unroll
      for (int j = 0; j < 8; ++j) acc[j] = (float)tv.e[j];
    } else {
      int pos = orow - 1;
      int ot = pos / (oH * oW), r = pos % (oH * oW);
      int oh = r / oW, ow = r % oW;
      const float* wrow = pwl + cg * 8 + (cg >> 2) * 4;
#pragma unroll
      for (int kt = 0; kt < 3; ++kt) {
        int it = ot + kt - 1;
        if (it < 0 || it >= T0_) continue;
#pragma unroll
        for (int kh = 0; kh < 3; ++kh) {
          int ih = oh * sHW + kh - 1;
          if (ih < 0 || ih >= H0_) continue;
#pragma unroll
          for (int kw = 0; kw < 3; ++kw) {
            int iw = ow * sHW + kw - 1;
            if (iw < 0 || iw >= W0_) continue;
            int n = 1 + (it * H0_ + ih) * W0_ + iw;
            int widx = (kt * 3 + kh) * 3 + kw;
            union { uint4 u; bf16 e[8]; } tv;
            tv.u = *(const uint4*)(base + (size_t)n * 2304);
            const float* w = wrow + widx * 104;
            float wv_[8];
            *(float4*)&wv_[0] = *(const float4*)w;
            *(float4*)&wv_[4] = *(const float4*)(w + 4);
#pragma unroll
            for (int j = 0; j < 8; ++j) acc[j] += (float)tv.e[j] * wv_[j];
          }
        }
      }
    }
  }

  float s = 0.f, s2 = 0.f;
#pragma unroll
  for (int j = 0; j < 8; ++j) { s += acc[j]; s2 += acc[j] * acc[j]; }
#pragma unroll
  for (int mk = 1; mk < 16; mk <<= 1) {
    s += __shfl_xor(s, mk);
    s2 += __shfl_xor(s2, mk);
  }
  float mean = s * (1.f / 96.f);
  float var = s2 * (1.f / 96.f) - mean * mean;
  float rstd = rsqrtf(var + 1e-5f);

  if (act) {
    float gv[8], bv[8];
    *(float4*)&gv[0] = *(const float4*)(g + cg * 8);
    *(float4*)&gv[4] = *(const float4*)(g + cg * 8 + 4);
    *(float4*)&bv[0] = *(const float4*)(bt + cg * 8);
    *(float4*)&bv[4] = *(const float4*)(bt + cg * 8 + 4);
    union { uint4 u; bf16 e[8]; } ov;
#pragma unroll
    for (int j = 0; j < 8; ++j)
      ov.e[j] = __float2bfloat16((acc[j] - mean) * rstd * gv[j] + bv[j]);
    *(uint4*)(outp + ((size_t)bh * Lout + orow) * 96 + cg * 8) = ov.u;
  }
}

// ------------------------- V transpose: [bh][key][96] -> [bh][96][448] (pad 0)
__global__ __launch_bounds__(256) void vtran(
    const bf16* __restrict__ vp, bf16* __restrict__ vt) {
  __shared__ __align__(16) bf16 tile[64][104];
  const int tid = threadIdx.x;
  const int bh = blockIdx.y, kt0 = blockIdx.x * 64;
  const bf16* src = vp + (size_t)bh * LK_ * HD_;
  for (int c = tid; c < 768; c += 256) {
    int row = c / 12, seg = c % 12;
    int key = kt0 + row;
    uint4 v = {0u, 0u, 0u, 0u};
    if (key < LK_) v = *(const uint4*)(src + (size_t)key * HD_ + seg * 8);
    *(uint4*)&tile[row][seg * 8] = v;
  }
  __syncthreads();
  bf16* dst = vt + (size_t)bh * 96 * 448 + kt0;
  for (int c = tid; c < 768; c += 256) {
    int d = c >> 3, ch = c & 7;
    union { uint4 u; bf16 e[8]; } o;
#pragma unroll
    for (int j = 0; j < 8; ++j) o.e[j] = tile[ch * 8 + j][d];
    *(uint4*)(dst + (size_t)d * 448 + ch * 8) = o.u;
  }
}

// ------------------------------------- rel-pos dot tables (precompute kernel)
// relq[bh][p][24] f32: slots 0..7 = t(kt), 8..14 = h(kh), 16..22 = w(kw).
__global__ __launch_bounds__(256) void rel_dots(
    const bf16* __restrict__ qp, const float* __restrict__ rpt,
    const float* __restrict__ rph, const float* __restrict__ rpw,
    float* __restrict__ relq) {
  __shared__ float tab[69 * 100];              // rows: t 0..14, h 15..41, w 42..68
  __shared__ __align__(16) bf16 Qls[64][96];
  const int tid = threadIdx.x;
  const int bh = blockIdx.y;
  const int q0 = blockIdx.x * 64;
  const bf16* qb = qp + (size_t)bh * N_ * HD_;

  for (int i = tid; i < 69 * 24; i += 256) {
    int row = i / 24, c4 = (i % 24) * 4;
    const float* src = row < 15 ? rpt + row * 96
                      : row < 42 ? rph + (row - 15) * 96
                                 : rpw + (row - 42) * 96;
    *(float4*)&tab[row * 100 + c4] = *(const float4*)(src + c4);
  }
  for (int c = tid; c < 768; c += 256) {
    int row = c / 12, seg = c % 12;
    int p = q0 + row;
    if (p >= N_) p = N_ - 1;
    *(uint4*)&Qls[row][seg * 8] = *(const uint4*)(qb + (size_t)p * HD_ + seg * 8);
  }
  __syncthreads();

  const int r8 = tid >> 5, slot = tid & 31;
  if (slot == 15 || slot >= 23) return;  // no barriers after this point
  for (int g = 0; g < 8; ++g) {
    int row = g * 8 + r8;
    int p = q0 + row;
    if (p < 1 || p >= N_) continue;
    int pos = p - 1;
    int qt = pos / 196, rr = pos % 196;
    int qh = rr / 14, qw = rr % 14;
    int ti = slot < 8 ? qt - slot + 7
            : slot < 15 ? 15 + (qh - 2 * (slot - 8) + 12)
                        : 42 + (qw - 2 * (slot - 16) + 12);
    const float* trow = &tab[ti * 100];
    float acc = 0.f;
#pragma unroll
    for (int d4 = 0; d4 < 24; ++d4) {
      float4 w = *(const float4*)(trow + d4 * 4);
      union { uint2 u; unsigned short s[4]; } qv;
      qv.u = *(const uint2*)&Qls[row][d4 * 4];
      acc += w.x * b2f(qv.s[0]) + w.y * b2f(qv.s[1]) +
             w.z * b2f(qv.s[2]) + w.w * b2f(qv.s[3]);
    }
    relq[((size_t)bh * N_ + p) * 24 + slot] = acc;
  }
}

// ------------------------------------------------- MFMA flash attention (v6)
// R3's proven 2-barrier structure; V staged via global_load_lds from the
// pre-transposed vtb (linear LDS dest + pre-swizzled global src). K reg-staged
// into padded Ks. LDS 40960 B (4 blocks/CU). Q A-frags in registers.
__global__ __launch_bounds__(256) void attn_fused(
    const bf16* __restrict__ qp, const bf16* __restrict__ kp,
    const bf16* __restrict__ vtb, const float* __restrict__ relq,
    bf16* __restrict__ aout) {
  __shared__ __align__(16) bf16 Ks[64][104];    // 13312 B (pad 96->104)
  __shared__ __align__(16) bf16 VtS[96 * 64];   // 12288 B [d][key^swz]
  __shared__ __align__(16) bf16 Ps[4][16][72];  //  9216 B per-wave P tile
  __shared__ float relb[64][24];                //  6144 B

  const int tid = threadIdx.x;
  const int wv = tid >> 6, lane = tid & 63;
  const int col = lane & 15, quad = lane >> 4;
  const int bh = blockIdx.y;
  const int b = bh >> 3;
  const int h = bh & 7;
  const int q0 = blockIdx.x * 64;
  const bf16* qb = qp + (size_t)bh * N_ * HD_;
  const bf16* kb = kp + (size_t)bh * LK_ * HD_;
  const bf16* vt = vtb + (size_t)bh * 96 * 448;
  const float scale = 0.102062072615966f;  // 96^-0.5

  // ---- fill relb from precomputed global (vectorized; visible after (2)) ----
  {
    int nrow = N_ - q0;
    if (nrow > 64) nrow = 64;
    int n4 = nrow * 6;  // uint4 count (24 f32 per row)
    const uint4* src = (const uint4*)(relq + ((size_t)bh * N_ + q0) * 24);
    for (int i = tid; i < n4; i += 256) ((uint4*)relb)[i] = src[i];
  }

  // ---- Q A-fragments held in registers for whole k-loop ----
  int qrow = q0 + wv * 16 + col;
  if (qrow >= N_) qrow = N_ - 1;
  bf16x8 qa[3];
#pragma unroll
  for (int ks_ = 0; ks_ < 3; ++ks_)
    qa[ks_] = *(const bf16x8*)(qb + (size_t)qrow * HD_ + ks_ * 32 + quad * 8);

  // ---- hoisted staging geometry ----
  int krow[3], kseg[3];       // K: thread's 3 chunks of the 64x96 tile
  int voff[3];                // V: per-lane pre-swizzled source elem offset
  bf16* vdst[3];              // V: wave-uniform LDS dest base
#pragma unroll
  for (int i = 0; i < 3; ++i) {
    int c = tid + i * 256;
    krow[i] = c / 12;
    kseg[i] = (c % 12) * 8;
    int ci = wv * 192 + i * 64 + lane;       // chunk index in VtS (16B units)
    int d = ci >> 3, j0 = (ci & 7) * 8;
    int c_ = (d ^ (d >> 3)) & 7;
    voff[i] = d * 448 + (j0 ^ (c_ * 8));
    vdst[i] = (bf16*)VtS + (size_t)(wv * 192 + i * 64) * 8;
  }

  // ---- flash state (4 q rows per lane: row = wv*16 + quad*4 + r) ----
  float mrun[4] = {-1e30f, -1e30f, -1e30f, -1e30f};
  float lrun[4] = {0.f, 0.f, 0.f, 0.f};
  f32x4 oacc[6];
#pragma unroll
  for (int dt = 0; dt < 6; ++dt) oacc[dt] = (f32x4){0.f, 0.f, 0.f, 0.f};

  for (int kt_i = 0; kt_i < 7; ++kt_i) {
    const int kt0 = kt_i * 64;
    __syncthreads();  // (1) prior reads of Ks/VtS done; relb visible (iter 0)
    // ---- stage K (reg path, padded rows) + V^T (global_load_lds, linear) ----
#pragma unroll
    for (int i = 0; i < 3; ++i) {
      int key = kt0 + krow[i];
      if (key >= LK_) key = LK_ - 1;
      *(uint4*)&Ks[krow[i]][kseg[i]] =
          *(const uint4*)(kb + (size_t)key * HD_ + kseg[i]);
      gl_lds16(vt + voff[i] + kt0, vdst[i]);
    }
    __syncthreads();  // (2) tiles ready (compiler drains vmcnt+lgkmcnt)

    // ---- S = Q K^T ----
    f32x4 sacc[4];
#pragma unroll
    for (int jt = 0; jt < 4; ++jt) sacc[jt] = (f32x4){0.f, 0.f, 0.f, 0.f};
#pragma unroll
    for (int ks_ = 0; ks_ < 3; ++ks_) {
#pragma unroll
      for (int jt = 0; jt < 4; ++jt) {
        bf16x8 bk = *(const bf16x8*)&Ks[jt * 16 + col][ks_ * 32 + quad * 8];
        sacc[jt] = __builtin_amdgcn_mfma_f32_16x16x32_bf16(qa[ks_], bk, sacc[jt], 0, 0, 0);
      }
    }

    // ---- scale + rel-pos bias + validity ----
    float sv[4][4];  // [jt][reg]
#pragma unroll
    for (int jt = 0; jt < 4; ++jt) {
      int kglob = kt0 + jt * 16 + col;
      bool kvalid = (kglob < LK_);
      int kbod = (kglob >= 1) ? kglob - 1 : 0;
      int kt_ = kbod / 49, krem = kbod % 49;
      int kh_ = krem / 7, kw_ = krem % 7;
#pragma unroll
      for (int r = 0; r < 4; ++r) {
        int qr = wv * 16 + quad * 4 + r;
        int p = q0 + qr;
        float s = sacc[jt][r] * scale;
        if (kvalid && kglob >= 1 && p >= 1 && p < N_)
          s += relb[qr][kt_] + relb[qr][8 + kh_] + relb[qr][16 + kw_];
        if (!kvalid) s = -1e30f;
        sv[jt][r] = s;
      }
    }

    // ---- online softmax (row spread over 16-lane cluster) ----
    float pexp[4][4];
#pragma unroll
    for (int r = 0; r < 4; ++r) {
      float pm = fmaxf(fmaxf(sv[0][r], sv[1][r]), fmaxf(sv[2][r], sv[3][r]));
#pragma unroll
      for (int mk = 1; mk < 16; mk <<= 1) pm = fmaxf(pm, __shfl_xor(pm, mk));
      float mn = fmaxf(mrun[r], pm);
      float alpha = __expf(mrun[r] - mn);
      mrun[r] = mn;
      float rs = 0.f;
#pragma unroll
      for (int jt = 0; jt < 4; ++jt) {
        float e = __expf(sv[jt][r] - mn);
        pexp[jt][r] = e;
        rs += e;
      }
#pragma unroll
      for (int mk = 1; mk < 16; mk <<= 1) rs += __shfl_xor(rs, mk);
      lrun[r] = lrun[r] * alpha + rs;
#pragma unroll
      for (int dt = 0; dt < 6; ++dt) {
        oacc[dt][r] *= alpha;
      }
    }

    // ---- P (C-layout) -> LDS -> A-layout (wave-private region) ----
#pragma unroll
    for (int jt = 0; jt < 4; ++jt)
#pragma unroll
      for (int r = 0; r < 4; ++r)
        Ps[wv][quad * 4 + r][jt * 16 + col] = __float2bfloat16(pexp[jt][r]);
    // same-wave DS ordering: compiler's lgkmcnt wait orders write->read

    // ---- O += P V ----
#pragma unroll
    for (int ks_ = 0; ks_ < 2; ++ks_) {
      bf16x8 ap = *(const bf16x8*)&Ps[wv][col][ks_ * 32 + quad * 8];
#pragma unroll
      for (int dt = 0; dt < 6; ++dt) {
        int d = dt * 16 + col;
        int c_ = (d ^ (d >> 3)) & 7;
        bf16x8 bv =
            *(const bf16x8*)&VtS[d * 64 + ((ks_ * 32 + quad * 8) ^ (c_ << 3))];
        oacc[dt] = __builtin_amdgcn_mfma_f32_16x16x32_bf16(ap, bv, oacc[dt], 0, 0, 0);
      }
    }
  }

  // ---- epilogue: O/l + residual q (re-read global, L2-hot), store bf16 ----
#pragma unroll
  for (int r = 0; r < 4; ++r) {
    int qr = wv * 16 + quad * 4 + r;
    int p = q0 + qr;
    if (p >= N_) continue;
    float inv = 1.f / lrun[r];
#pragma unroll
    for (int dt = 0; dt < 6; ++dt) {
      int d = dt * 16 + col;
      float val = oacc[dt][r] * inv;
      if (p >= 1) val += (float)qb[(size_t)p * HD_ + d];
      aout[((size_t)b * N_ + p) * DIM_ + h * HD_ + d] = __float2bfloat16(val);
    }
  }
}

// ------------------------------------------------------------------- launch
extern "C" void kernel_launch(void* const* d_in, const int* in_sizes, int n_in,
                              void* d_out, int out_size, void* d_ws,
                              size_t ws_size, hipStream_t stream) {
  (void)in_sizes; (void)n_in; (void)out_size; (void)ws_size;
  const float* x      = (const float*)d_in[0];
  const float* qkv_w  = (const float*)d_in[1];
  const float* qkv_b  = (const float*)d_in[2];
  const float* pool_q = (const float*)d_in[3];
  const float* pool_k = (const float*)d_in[4];
  const float* pool_v = (const float*)d_in[5];
  const float* ln_q_g = (const float*)d_in[6];
  const float* ln_q_b = (const float*)d_in[7];
  const float* ln_k_g = (const float*)d_in[8];
  const float* ln_k_b = (const float*)d_in[9];
  const float* ln_v_g = (const float*)d_in[10];
  const float* ln_v_b = (const float*)d_in[11];
  const float* rph    = (const float*)d_in[12];
  const float* rpw    = (const float*)d_in[13];
  const float* rpt    = (const float*)d_in[14];
  const float* proj_w = (const float*)d_in[15];
  const float* proj_b = (const float*)d_in[16];

  char* ws = (char*)d_ws;
  bf16* wt_qkv  = (bf16*)(ws);                  // 2304x768 bf16   (3.54 MB)
  bf16* wt_proj = (bf16*)(ws + 3538944);        // 768x768 bf16    (1.18 MB)
  bf16* xb      = (bf16*)(ws + 4718592);        // 25104x768 bf16  (38.6 MB)
  bf16* aout    = xb;                           // reuse: xb dead after gemm#1
  bf16* qkv     = (bf16*)(ws + 43278336);       // 25104x2304 bf16 (115.7 MB)
  float* relq   = (float*)(ws + 43278336);      // aliases qkv (19.3 MB)
  bf16* vtb     = (bf16*)(ws + 63278336);       // aliases qkv (+11.0 MB)
  bf16* qpoolb  = (bf16*)(ws + 158957568);      // 128x1569x96 bf16 (38.6 MB)
  bf16* kpoolb  = (bf16*)(ws + 197517312);      // 128x393x96 bf16  (9.7 MB)
  bf16* vpoolb  = (bf16*)(ws + 207175680);      // 128x393x96 bf16  (9.7 MB)
  float* pwT    = (float*)(ws + 216834048);     // 3x27x96 fp32     (31 KB)
  float* outp   = (float*)d_out;                // fp32 output per reference

  int n4 = (B_ * N_ * DIM_) / 4;
  cvt_f32_bf16<<<(n4 + 255) / 256, 256, 0, stream>>>(x, xb, n4);
  transpose_f32_bf16<<<dim3(72, 24), dim3(32, 8), 0, stream>>>(qkv_w, wt_qkv, 768, 2304);
  transpose_f32_bf16<<<dim3(24, 24), dim3(32, 8), 0, stream>>>(proj_w, wt_proj, 768, 768);
  prep_pw<<<11, 256, 0, stream>>>(pool_q, pool_k, pool_v, pwT);

  gemm_bt<bf16><<<197 * 18, 256, 0, stream>>>(xb, wt_qkv, qkv_b, qkv,
                                              B_ * N_, 3 * DIM_, DIM_);

  pool_ln<<<dim3(99, 128), 256, 0, stream>>>(qkv, pwT, ln_q_g, ln_q_b, qpoolb,
                                             0, 1, 14, 14, N_);
  pool_ln<<<dim3(25, 128), 256, 0, stream>>>(qkv, pwT + 2592, ln_k_g, ln_k_b,
                                             kpoolb, 1, 2, 7, 7, LK_);
  pool_ln<<<dim3(25, 128), 256, 0, stream>>>(qkv, pwT + 5184, ln_v_g, ln_v_b,
                                             vpoolb, 2, 2, 7, 7, LK_);

  // qkv buffer is dead after the pools; relq + vtb alias it.
  vtran<<<dim3(7, 128), 256, 0, stream>>>(vpoolb, vtb);
  rel_dots<<<dim3(25, 128), 256, 0, stream>>>(qpoolb, rpt, rph, rpw, relq);

  attn_fused<<<dim3(25, 128), 256, 0, stream>>>(qpoolb, kpoolb, vtb, relq,
                                                aout);

  gemm_bt<float><<<197 * 6, 256, 0, stream>>>(aout, wt_proj, proj_b, outp,
                                              B_ * N_, DIM_, DIM_);
}